// Round 5
// baseline (1257.085 us; speedup 1.0000x reference)
//
#include <hip/hip_runtime.h>

#define B_    128
#define NSTEP 24
#define INL   512
#define OUTL  256
#define HL    1024
#define CL    1024
#define IH    (INL + HL)   // 1536

typedef short s16x8 __attribute__((ext_vector_type(8)));
typedef float f32x4 __attribute__((ext_vector_type(4)));

// ws layout (proven safe in R4: canary at 64+768K survived):
//   [0,4)          dtype flag
//   [64, 64+256K)  c  as fp16  [128][1024]
//   [64+256K, ..)  hA as bf16  [128][1024]
//   [64+512K, ..)  hB as bf16  [128][1024]
#define WS_C  64
#define WS_HA (64 + 262144)
#define WS_HB (64 + 524288)

__device__ __forceinline__ float bits2f(unsigned short u) {
    union { unsigned u; float f; } w; w.u = ((unsigned)u) << 16; return w.f;
}
__device__ __forceinline__ unsigned short f2bf(float f) {
    union { float f; unsigned u; } w; w.f = f;
    unsigned r = (w.u + 0x7fffu + ((w.u >> 16) & 1u)) >> 16;   // RNE
    return (unsigned short)r;
}
__device__ __forceinline__ float sigmoidf_(float v) { return 1.0f / (1.0f + expf(-v)); }
__device__ __forceinline__ float sane(float v, float lim) {   // NaN -> bounded
    return fminf(fmaxf(v, -lim), lim);
}

// Dual-dtype loaders: FP32=1 -> fp32 data converted to bf16; FP32=0 -> bf16 data.
template<int FP32>
__device__ __forceinline__ s16x8 load8(const void* base, size_t off) {
    if constexpr (FP32) {
        const float* p = (const float*)base + off;
        f32x4 a = *(const f32x4*)p;
        f32x4 b = *(const f32x4*)(p + 4);
        s16x8 r;
        r[0] = (short)f2bf(a[0]); r[1] = (short)f2bf(a[1]);
        r[2] = (short)f2bf(a[2]); r[3] = (short)f2bf(a[3]);
        r[4] = (short)f2bf(b[0]); r[5] = (short)f2bf(b[1]);
        r[6] = (short)f2bf(b[2]); r[7] = (short)f2bf(b[3]);
        return r;
    } else {
        return *(const s16x8*)((const unsigned short*)base + off);
    }
}
template<int FP32>
__device__ __forceinline__ float ld1(const void* base, size_t off) {
    if constexpr (FP32) return ((const float*)base)[off];
    else                return bits2f(((const unsigned short*)base)[off]);
}

// ---------------------------------------------------------------------------
// Dtype detector on x's first 1024 dwords (kept for robustness; verified to
// return flag=1 on this harness in R4). flag=1 means fp32 inputs.
// ---------------------------------------------------------------------------
__global__ void detect_kernel(const unsigned* __restrict__ xw, int* __restrict__ flag) {
    __shared__ int wild, zero;
    const int tid = threadIdx.x;
    if (tid == 0) { wild = 0; zero = 0; }
    __syncthreads();
    int w = 0, z = 0;
    for (int s = 0; s < 4; ++s) {
        unsigned short lo = (unsigned short)(xw[tid * 4 + s] & 0xffffu);
        float v = bits2f(lo);
        if (v == 0.0f) z++;
        else if (v == v && (fabsf(v) > 1e4f || fabsf(v) < 1e-8f)) w++;
    }
    atomicAdd(&wild, w);
    atomicAdd(&zero, z);
    __syncthreads();
    if (tid == 0) *flag = (wild > 128 || zero > 512) ? 1 : 0;
}

// ---------------------------------------------------------------------------
// Gate GEMM (4 gates fused) + LSTM cell update for one timestep.
// Grid: 256 WGs x 256 thr. WG owns 4 h-cols x 4 gates = 16 MFMA N-cols.
// GEMM mechanics + C/D layout verified on HW in R4 (scalar cross-check green).
// ---------------------------------------------------------------------------
template<int FP32>
__device__ __forceinline__ void gate_body(
    const void* __restrict__ x,
    const void* __restrict__ W,  const void* __restrict__ Wi,
    const void* __restrict__ Wf, const void* __restrict__ Wo,
    const void* __restrict__ bz, const void* __restrict__ bi,
    const void* __restrict__ bfg, const void* __restrict__ bo,
    _Float16* __restrict__ c,
    const unsigned short* __restrict__ hprev,
    unsigned short* __restrict__ hnext, int t)
{
    const int tid  = threadIdx.x;
    const int lane = tid & 63;
    const int wv   = tid >> 6;
    const int j0   = blockIdx.x * 4;
    const int c16  = lane & 15;
    const int g    = c16 >> 2;
    const int jj   = c16 & 3;
    const int kg   = lane >> 4;

    const void* Wg = (g == 0) ? W : (g == 1) ? Wi : (g == 2) ? Wf : Wo;
    const size_t woff = ((size_t)t * CL + (j0 + jj)) * IH + kg * 8;

    const int row0 = wv * 32 + c16;
    const int row1 = row0 + 16;

    f32x4 acc0 = {0.f, 0.f, 0.f, 0.f};
    f32x4 acc1 = {0.f, 0.f, 0.f, 0.f};

    // K phase 1: x part (k = 0..511)
    {
        const size_t a0 = ((size_t)row0 * NSTEP + t) * INL + kg * 8;
        const size_t a1 = ((size_t)row1 * NSTEP + t) * INL + kg * 8;
        #pragma unroll 4
        for (int kb = 0; kb < INL; kb += 32) {
            s16x8 av0 = load8<FP32>(x, a0 + kb);
            s16x8 av1 = load8<FP32>(x, a1 + kb);
            s16x8 bv  = load8<FP32>(Wg, woff + kb);
            acc0 = __builtin_amdgcn_mfma_f32_16x16x32_bf16(av0, bv, acc0, 0, 0, 0);
            acc1 = __builtin_amdgcn_mfma_f32_16x16x32_bf16(av1, bv, acc1, 0, 0, 0);
        }
    }
    // K phase 2: h part (k = 512..1535); h is always bf16 (our ws buffer)
    {
        const unsigned short* a0 = hprev + (size_t)row0 * HL + kg * 8;
        const unsigned short* a1 = hprev + (size_t)row1 * HL + kg * 8;
        const size_t w2 = woff + INL;
        #pragma unroll 4
        for (int kb = 0; kb < HL; kb += 32) {
            s16x8 av0 = *(const s16x8*)(a0 + kb);
            s16x8 av1 = *(const s16x8*)(a1 + kb);
            s16x8 bv  = load8<FP32>(Wg, w2 + kb);
            acc0 = __builtin_amdgcn_mfma_f32_16x16x32_bf16(av0, bv, acc0, 0, 0, 0);
            acc1 = __builtin_amdgcn_mfma_f32_16x16x32_bf16(av1, bv, acc1, 0, 0, 0);
        }
    }

    // Stage pre-bias logits to LDS: lg[gate][jj][batchrow].
    // C/D layout: col = lane&15, row = (lane>>4)*4 + i   [m89 + R4 on-HW verified]
    __shared__ float lg[4][4][B_];
    #pragma unroll
    for (int i = 0; i < 4; ++i) {
        lg[g][jj][wv * 32 + kg * 4 + i]      = acc0[i];
        lg[g][jj][wv * 32 + 16 + kg * 4 + i] = acc1[i];
    }
    __syncthreads();

    // Cell update: 512 (b, j) items over 256 threads.
    #pragma unroll
    for (int p = 0; p < 2; ++p) {
        const int idx = tid + p * 256;
        const int b   = idx & 127;
        const int jl  = idx >> 7;
        const int jg  = j0 + jl;
        const float z  = tanhf   (sane(lg[0][jl][b] + ld1<FP32>(bz,  t * CL + jg), 30.f));
        const float zi = sigmoidf_(sane(lg[1][jl][b] + ld1<FP32>(bi,  t * CL + jg), 30.f));
        const float zf = sigmoidf_(sane(lg[2][jl][b] + ld1<FP32>(bfg, t * CL + jg), 30.f));
        const float zo = sigmoidf_(sane(lg[3][jl][b] + ld1<FP32>(bo,  t * CL + jg), 30.f));
        const float cold = (float)c[(size_t)b * CL + jg];
        const float cn   = sane(zf * cold + zi * z, 50.f);
        c[(size_t)b * CL + jg] = (_Float16)cn;
        hnext[(size_t)b * HL + jg] = f2bf(zo * tanhf(cn));
    }
}

__global__ __launch_bounds__(256, 1) void gate_cell_kernel(
    const void* x, const void* W, const void* Wi, const void* Wf, const void* Wo,
    const void* bz, const void* bi, const void* bfg, const void* bo,
    const int* __restrict__ flag, _Float16* c,
    const unsigned short* hprev, unsigned short* hnext, int t)
{
    if (*flag) gate_body<1>(x, W, Wi, Wf, Wo, bz, bi, bfg, bo, c, hprev, hnext, t);
    else       gate_body<0>(x, W, Wi, Wf, Wo, bz, bi, bfg, bo, c, hprev, hnext, t);
}

// ---------------------------------------------------------------------------
// Output projection: y = sigmoid(h @ Wout^T + bout) -> out[b][t*256+o], FP32.
// Grid: 16 WGs x 256 thr.
// ---------------------------------------------------------------------------
template<int FP32>
__device__ __forceinline__ void outproj_body(
    const unsigned short* __restrict__ h, const void* __restrict__ Wout,
    const void* __restrict__ bout, float* __restrict__ out, int t)
{
    const int tid  = threadIdx.x;
    const int lane = tid & 63;
    const int wv   = tid >> 6;
    const int o    = blockIdx.x * 16 + (lane & 15);
    const int kg   = lane >> 4;

    const size_t woff = ((size_t)t * OUTL + o) * HL + kg * 8;
    const int row0 = wv * 32 + (lane & 15);
    const int row1 = row0 + 16;
    const unsigned short* a0 = h + (size_t)row0 * HL + kg * 8;
    const unsigned short* a1 = h + (size_t)row1 * HL + kg * 8;

    f32x4 acc0 = {0.f, 0.f, 0.f, 0.f};
    f32x4 acc1 = {0.f, 0.f, 0.f, 0.f};
    #pragma unroll 4
    for (int kb = 0; kb < HL; kb += 32) {
        s16x8 av0 = *(const s16x8*)(a0 + kb);
        s16x8 av1 = *(const s16x8*)(a1 + kb);
        s16x8 bv  = load8<FP32>(Wout, woff + kb);
        acc0 = __builtin_amdgcn_mfma_f32_16x16x32_bf16(av0, bv, acc0, 0, 0, 0);
        acc1 = __builtin_amdgcn_mfma_f32_16x16x32_bf16(av1, bv, acc1, 0, 0, 0);
    }

    const float bb = ld1<FP32>(bout, t * OUTL + o);
    #pragma unroll
    for (int i = 0; i < 4; ++i) {
        const int r0 = wv * 32 + kg * 4 + i;
        out[(size_t)r0 * (NSTEP * OUTL) + t * OUTL + o] =
            sigmoidf_(sane(acc0[i] + bb, 30.f));
        out[(size_t)(r0 + 16) * (NSTEP * OUTL) + t * OUTL + o] =
            sigmoidf_(sane(acc1[i] + bb, 30.f));
    }
}

__global__ __launch_bounds__(256, 1) void outproj_kernel(
    const unsigned short* h, const void* Wout, const void* bout,
    const int* __restrict__ flag, float* out, int t)
{
    if (*flag) outproj_body<1>(h, Wout, bout, out, t);
    else       outproj_body<0>(h, Wout, bout, out, t);
}

// ---------------------------------------------------------------------------
// Broadcast c0 (-> fp16) and h0 (-> bf16, both buffers).
// ---------------------------------------------------------------------------
__global__ void init_kernel(const void* c0, const void* h0, const int* __restrict__ flag,
                            _Float16* __restrict__ c,
                            unsigned short* __restrict__ hA,
                            unsigned short* __restrict__ hB)
{
    const int f   = *flag;
    const int idx = blockIdx.x * blockDim.x + threadIdx.x;
    if (idx < B_ * CL) {
        const int j = idx & (CL - 1);
        const float cv = f ? ((const float*)c0)[j] : bits2f(((const unsigned short*)c0)[j]);
        const float hv = f ? ((const float*)h0)[j] : bits2f(((const unsigned short*)h0)[j]);
        c[idx]  = (_Float16)cv;
        const unsigned short hb = f2bf(hv);
        hA[idx] = hb;
        hB[idx] = hb;
    }
}

extern "C" void kernel_launch(void* const* d_in, const int* in_sizes, int n_in,
                              void* d_out, int out_size, void* d_ws, size_t ws_size,
                              hipStream_t stream)
{
    const void* x    = d_in[0];
    const void* W    = d_in[1];
    const void* Wi   = d_in[2];
    const void* Wf   = d_in[3];
    const void* Wo   = d_in[4];
    const void* Wout = d_in[5];
    const void* bz   = d_in[6];
    const void* bi   = d_in[7];
    const void* bfg  = d_in[8];
    const void* bo   = d_in[9];
    const void* bout = d_in[10];
    const void* c0   = d_in[11];
    const void* h0   = d_in[12];

    char* ws = (char*)d_ws;
    int*            flag = (int*)(ws + 0);
    _Float16*       c    = (_Float16*)(ws + WS_C);
    unsigned short* hA   = (unsigned short*)(ws + WS_HA);
    unsigned short* hB   = (unsigned short*)(ws + WS_HB);

    detect_kernel<<<1, 256, 0, stream>>>((const unsigned*)x, flag);
    init_kernel<<<512, 256, 0, stream>>>(c0, h0, flag, c, hA, hB);

    float* out = (float*)d_out;   // OUTPUT IS FP32 (R4 post-mortem evidence)
    for (int t = 0; t < NSTEP; ++t) {
        const unsigned short* hp = (t & 1) ? hB : hA;
        unsigned short*       hn = (t & 1) ? hA : hB;
        gate_cell_kernel<<<256, 256, 0, stream>>>(
            x, W, Wi, Wf, Wo, bz, bi, bfg, bo, flag, c, hp, hn, t);
        outproj_kernel<<<16, 256, 0, stream>>>(hn, Wout, bout, flag, out, t);
    }
}

// Round 6
// 1020.969 us; speedup vs baseline: 1.2313x; 1.2313x over previous
//
#include <hip/hip_runtime.h>

#define B_    128
#define NSTEP 24
#define INL   512
#define OUTL  256
#define HL    1024
#define CL    1024
#define IH    (INL + HL)   // 1536

typedef short          s16x8 __attribute__((ext_vector_type(8)));
typedef float          f32x4 __attribute__((ext_vector_type(4)));
typedef unsigned short u16x4 __attribute__((ext_vector_type(4)));

// ---------- full-path ws layout (needs 26,214,464 B) ----------
//   [0,4)        dtype flag
//   [64,  +512K) c  fp32 [128][1024]
//   [+,   +256K) hA bf16 [128][1024]
//   [+,   +256K) hB bf16 [128][1024]
//   [+,  +24MB)  XW fp16 [24][256][16][128]  (x-part logits, {g,jj}-packed)
#define FWS_C   64
#define FWS_HA  (FWS_C + 524288)
#define FWS_HB  (FWS_HA + 262144)
#define FWS_XW  (FWS_HB + 262144)
#define FWS_END (FWS_XW + 25165824)
// ---------- fallback (R5, proven) ws layout ----------
#define WS_C  64
#define WS_HA (64 + 262144)
#define WS_HB (64 + 524288)

__device__ __forceinline__ float bits2f(unsigned short u) {
    union { unsigned u; float f; } w; w.u = ((unsigned)u) << 16; return w.f;
}
__device__ __forceinline__ unsigned short f2bf(float f) {
    union { float f; unsigned u; } w; w.f = f;
    unsigned r = (w.u + 0x7fffu + ((w.u >> 16) & 1u)) >> 16;   // RNE
    return (unsigned short)r;
}
__device__ __forceinline__ float sigmoidf_(float v) { return 1.0f / (1.0f + expf(-v)); }
__device__ __forceinline__ float sane(float v, float lim) {   // NaN -> bounded
    return fminf(fmaxf(v, -lim), lim);
}

template<int FP32>
__device__ __forceinline__ s16x8 load8(const void* base, size_t off) {
    if constexpr (FP32) {
        const float* p = (const float*)base + off;
        f32x4 a = *(const f32x4*)p;
        f32x4 b = *(const f32x4*)(p + 4);
        s16x8 r;
        r[0] = (short)f2bf(a[0]); r[1] = (short)f2bf(a[1]);
        r[2] = (short)f2bf(a[2]); r[3] = (short)f2bf(a[3]);
        r[4] = (short)f2bf(b[0]); r[5] = (short)f2bf(b[1]);
        r[6] = (short)f2bf(b[2]); r[7] = (short)f2bf(b[3]);
        return r;
    } else {
        return *(const s16x8*)((const unsigned short*)base + off);
    }
}
template<int FP32>
__device__ __forceinline__ float ld1(const void* base, size_t off) {
    if constexpr (FP32) return ((const float*)base)[off];
    else                return bits2f(((const unsigned short*)base)[off]);
}

// ---------------------------------------------------------------------------
// Dtype detector (verified flag=1/fp32 on this harness in R4).
// ---------------------------------------------------------------------------
__global__ void detect_kernel(const unsigned* __restrict__ xw, int* __restrict__ flag) {
    __shared__ int wild, zero;
    const int tid = threadIdx.x;
    if (tid == 0) { wild = 0; zero = 0; }
    __syncthreads();
    int w = 0, z = 0;
    for (int s = 0; s < 4; ++s) {
        unsigned short lo = (unsigned short)(xw[tid * 4 + s] & 0xffffu);
        float v = bits2f(lo);
        if (v == 0.0f) z++;
        else if (v == v && (fabsf(v) > 1e4f || fabsf(v) < 1e-8f)) w++;
    }
    atomicAdd(&wild, w);
    atomicAdd(&zero, z);
    __syncthreads();
    if (tid == 0) *flag = (wild > 128 || zero > 512) ? 1 : 0;
}

// ===========================================================================
// FULL PATH
// ===========================================================================

// init: c fp32, h0 -> both bf16 buffers
__global__ void init_full_kernel(const void* c0, const void* h0, const int* __restrict__ flag,
                                 float* __restrict__ c,
                                 unsigned short* __restrict__ hA,
                                 unsigned short* __restrict__ hB)
{
    const int f   = *flag;
    const int idx = blockIdx.x * blockDim.x + threadIdx.x;
    if (idx < B_ * CL) {
        const int j = idx & (CL - 1);
        c[idx]  = f ? ((const float*)c0)[j] : bits2f(((const unsigned short*)c0)[j]);
        const float hv = f ? ((const float*)h0)[j] : bits2f(((const unsigned short*)h0)[j]);
        const unsigned short hb = f2bf(hv);
        hA[idx] = hb;
        hB[idx] = hb;
    }
}

// ---------------------------------------------------------------------------
// XW precompute: XW[t][grp][c16][b] = sum_k x[b][t][k] * Wg[t][grp*4+jj][k],
// k<512, c16 = g*4+jj packing (matches step kernel). Grid 24*256 = 6144 WGs,
// 256 thr; WG structure identical to the HW-verified R5 gate kernel phase 1.
// ---------------------------------------------------------------------------
template<int FP32>
__device__ __forceinline__ void xw_body(
    const void* __restrict__ x,
    const void* __restrict__ W,  const void* __restrict__ Wi,
    const void* __restrict__ Wf, const void* __restrict__ Wo,
    _Float16* __restrict__ XW)
{
    const int t    = blockIdx.x >> 8;    // /256
    const int grp  = blockIdx.x & 255;
    const int tid  = threadIdx.x;
    const int lane = tid & 63;
    const int wv   = tid >> 6;
    const int c16  = lane & 15;
    const int g    = c16 >> 2;
    const int jj   = c16 & 3;
    const int kg   = lane >> 4;
    const int j0   = grp * 4;

    const void* Wg = (g == 0) ? W : (g == 1) ? Wi : (g == 2) ? Wf : Wo;
    const size_t woff = ((size_t)t * CL + (j0 + jj)) * IH + kg * 8;

    const int row0 = wv * 32 + c16;
    const int row1 = row0 + 16;
    const size_t a0 = ((size_t)row0 * NSTEP + t) * INL + kg * 8;
    const size_t a1 = ((size_t)row1 * NSTEP + t) * INL + kg * 8;

    f32x4 acc0 = {0.f, 0.f, 0.f, 0.f};
    f32x4 acc1 = {0.f, 0.f, 0.f, 0.f};
    #pragma unroll 4
    for (int kb = 0; kb < INL; kb += 32) {
        s16x8 av0 = load8<FP32>(x, a0 + kb);
        s16x8 av1 = load8<FP32>(x, a1 + kb);
        s16x8 bv  = load8<FP32>(Wg, woff + kb);
        acc0 = __builtin_amdgcn_mfma_f32_16x16x32_bf16(av0, bv, acc0, 0, 0, 0);
        acc1 = __builtin_amdgcn_mfma_f32_16x16x32_bf16(av1, bv, acc1, 0, 0, 0);
    }

    // C/D layout: col=lane&15, row=(lane>>4)*4+i  [m89 + R4 on-HW verified]
    _Float16* dst = XW + (((size_t)t * 256 + grp) * 16 + c16) * B_;
    u16x4 p0, p1;
    #pragma unroll
    for (int i = 0; i < 4; ++i) {
        union { _Float16 h; unsigned short u; } w0, w1;
        w0.h = (_Float16)acc0[i]; w1.h = (_Float16)acc1[i];
        p0[i] = w0.u; p1[i] = w1.u;
    }
    *(u16x4*)(dst + wv * 32 + kg * 4)      = p0;
    *(u16x4*)(dst + wv * 32 + 16 + kg * 4) = p1;
}

__global__ __launch_bounds__(256, 2) void xw_kernel(
    const void* x, const void* W, const void* Wi, const void* Wf, const void* Wo,
    const int* __restrict__ flag, _Float16* XW)
{
    if (*flag) xw_body<1>(x, W, Wi, Wf, Wo, XW);
    else       xw_body<0>(x, W, Wi, Wf, Wo, XW);
}

// ---------------------------------------------------------------------------
// Combined step kernel, grid 64+1024 = 1088 WGs x 256 thr.
//  blocks 0..63    : outproj for step t-1 (reads same hprev) -- skipped at t=0
//  blocks 64..1087 : h-part gate GEMM (M=32/WG, K split 2 ways) + cell update
// Waves: mf = wv&1 (M-frag), kh = wv>>1 (K-half). LDS reduce over kh.
// ---------------------------------------------------------------------------
template<int FP32>
__device__ __forceinline__ void outproj_part(
    const unsigned short* __restrict__ h, const void* __restrict__ Wout,
    const void* __restrict__ bout, float* __restrict__ out, int tp, int og,
    float red[2][2][16][16])
{
    const int tid  = threadIdx.x;
    const int lane = tid & 63;
    const int wv   = tid >> 6;
    const int c16  = lane & 15;
    const int kg   = lane >> 4;
    const int mf   = wv & 1;
    const int kh   = wv >> 1;

    const int o0   = (og & 15) * 16;
    const int mgrp = og >> 4;
    const int o    = o0 + c16;

    const size_t woff = ((size_t)tp * OUTL + o) * HL + kh * 512 + kg * 8;
    const int row = mgrp * 32 + mf * 16 + c16;
    const unsigned short* a = h + (size_t)row * HL + kh * 512 + kg * 8;

    f32x4 acc = {0.f, 0.f, 0.f, 0.f};
    #pragma unroll 8
    for (int kb = 0; kb < 512; kb += 32) {
        s16x8 av = *(const s16x8*)(a + kb);
        s16x8 bv = load8<FP32>(Wout, woff + kb);
        acc = __builtin_amdgcn_mfma_f32_16x16x32_bf16(av, bv, acc, 0, 0, 0);
    }
    #pragma unroll
    for (int i = 0; i < 4; ++i) red[kh][mf][c16][kg * 4 + i] = acc[i];
    __syncthreads();

    const float bb = ld1<FP32>(bout, (size_t)tp * OUTL + o0 + (tid & 15));
    #pragma unroll
    for (int p = 0; p < 2; ++p) {
        const int idx = tid + p * 256;
        const int cc  = idx & 15;
        const int r   = idx >> 4;          // 0..31
        const int mff = r >> 4, rm = r & 15;
        const float lg = red[0][mff][cc][rm] + red[1][mff][cc][rm] + bb;
        out[(size_t)(mgrp * 32 + r) * (NSTEP * OUTL) + (size_t)tp * OUTL + o0 + cc] =
            sigmoidf_(sane(lg, 30.f));
    }
}

template<int FP32>
__device__ __forceinline__ void step_body(
    const void* __restrict__ W,  const void* __restrict__ Wi,
    const void* __restrict__ Wf, const void* __restrict__ Wo,
    const void* __restrict__ bz, const void* __restrict__ bi,
    const void* __restrict__ bfg, const void* __restrict__ bo,
    const void* __restrict__ Wout, const void* __restrict__ bout,
    const _Float16* __restrict__ XW,
    float* __restrict__ c,
    const unsigned short* __restrict__ hprev,
    unsigned short* __restrict__ hnext,
    float* __restrict__ out, int t)
{
    __shared__ float red[2][2][16][16];
    const int blk = blockIdx.x;

    if (blk < 64) {            // ---- outproj for t-1 ----
        if (t == 0) return;
        outproj_part<FP32>(hprev, Wout, bout, out, t - 1, blk, red);
        return;
    }

    // ---- gate h-GEMM + cell update ----
    const int gb   = blk - 64;
    const int grp  = gb & 255;
    const int mgrp = gb >> 8;            // 0..3
    const int tid  = threadIdx.x;
    const int lane = tid & 63;
    const int wv   = tid >> 6;
    const int c16  = lane & 15;
    const int g    = c16 >> 2;
    const int jj   = c16 & 3;
    const int kg   = lane >> 4;
    const int mf   = wv & 1;
    const int kh   = wv >> 1;
    const int j0   = grp * 4;

    const void* Wg = (g == 0) ? W : (g == 1) ? Wi : (g == 2) ? Wf : Wo;
    const size_t woff = ((size_t)t * CL + (j0 + jj)) * IH + INL + kh * 512 + kg * 8;
    const int row = mgrp * 32 + mf * 16 + c16;
    const unsigned short* a = hprev + (size_t)row * HL + kh * 512 + kg * 8;

    f32x4 acc = {0.f, 0.f, 0.f, 0.f};
    #pragma unroll 8
    for (int kb = 0; kb < 512; kb += 32) {
        s16x8 av = *(const s16x8*)(a + kb);
        s16x8 bv = load8<FP32>(Wg, woff + kb);
        acc = __builtin_amdgcn_mfma_f32_16x16x32_bf16(av, bv, acc, 0, 0, 0);
    }
    #pragma unroll
    for (int i = 0; i < 4; ++i) red[kh][mf][c16][kg * 4 + i] = acc[i];
    __syncthreads();

    // cell update: 32 rows x 4 cols = 128 items on tid<128
    if (tid < 128) {
        const int r   = tid & 31;
        const int j_  = tid >> 5;          // 0..3
        const int mff = r >> 4, rm = r & 15;
        const int b   = mgrp * 32 + r;
        const int jg  = j0 + j_;
        const _Float16* xwp = XW + (((size_t)t * 256 + grp) * 16) * B_ + b;
        #define GLOGIT(gg) (red[0][mff][(gg)*4 + j_][rm] + red[1][mff][(gg)*4 + j_][rm] \
                            + (float)xwp[((gg)*4 + j_) * B_])
        const float z  = tanhf   (sane(GLOGIT(0) + ld1<FP32>(bz,  (size_t)t * CL + jg), 30.f));
        const float zi = sigmoidf_(sane(GLOGIT(1) + ld1<FP32>(bi,  (size_t)t * CL + jg), 30.f));
        const float zf = sigmoidf_(sane(GLOGIT(2) + ld1<FP32>(bfg, (size_t)t * CL + jg), 30.f));
        const float zo = sigmoidf_(sane(GLOGIT(3) + ld1<FP32>(bo,  (size_t)t * CL + jg), 30.f));
        #undef GLOGIT
        const float cold = c[(size_t)b * CL + jg];
        const float cn   = sane(zf * cold + zi * z, 50.f);
        c[(size_t)b * CL + jg] = cn;
        hnext[(size_t)b * HL + jg] = f2bf(zo * tanhf(cn));
    }
}

__global__ __launch_bounds__(256, 4) void step_kernel(
    const void* W, const void* Wi, const void* Wf, const void* Wo,
    const void* bz, const void* bi, const void* bfg, const void* bo,
    const void* Wout, const void* bout,
    const int* __restrict__ flag, const _Float16* XW, float* c,
    const unsigned short* hprev, unsigned short* hnext, float* out, int t)
{
    if (*flag) step_body<1>(W, Wi, Wf, Wo, bz, bi, bfg, bo, Wout, bout, XW, c, hprev, hnext, out, t);
    else       step_body<0>(W, Wi, Wf, Wo, bz, bi, bfg, bo, Wout, bout, XW, c, hprev, hnext, out, t);
}

// final outproj for t=23 (reads h(24)), grid 64
__global__ __launch_bounds__(256, 4) void outproj_final_kernel(
    const unsigned short* h, const void* Wout, const void* bout,
    const int* __restrict__ flag, float* out)
{
    __shared__ float red[2][2][16][16];
    if (*flag) outproj_part<1>(h, Wout, bout, out, NSTEP - 1, blockIdx.x, red);
    else       outproj_part<0>(h, Wout, bout, out, NSTEP - 1, blockIdx.x, red);
}

// ===========================================================================
// FALLBACK PATH (R5 verbatim, proven)
// ===========================================================================
template<int FP32>
__device__ __forceinline__ void gate_body(
    const void* __restrict__ x,
    const void* __restrict__ W,  const void* __restrict__ Wi,
    const void* __restrict__ Wf, const void* __restrict__ Wo,
    const void* __restrict__ bz, const void* __restrict__ bi,
    const void* __restrict__ bfg, const void* __restrict__ bo,
    _Float16* __restrict__ c,
    const unsigned short* __restrict__ hprev,
    unsigned short* __restrict__ hnext, int t)
{
    const int tid  = threadIdx.x;
    const int lane = tid & 63;
    const int wv   = tid >> 6;
    const int j0   = blockIdx.x * 4;
    const int c16  = lane & 15;
    const int g    = c16 >> 2;
    const int jj   = c16 & 3;
    const int kg   = lane >> 4;

    const void* Wg = (g == 0) ? W : (g == 1) ? Wi : (g == 2) ? Wf : Wo;
    const size_t woff = ((size_t)t * CL + (j0 + jj)) * IH + kg * 8;
    const int row0 = wv * 32 + c16;
    const int row1 = row0 + 16;

    f32x4 acc0 = {0.f, 0.f, 0.f, 0.f};
    f32x4 acc1 = {0.f, 0.f, 0.f, 0.f};
    {
        const size_t a0 = ((size_t)row0 * NSTEP + t) * INL + kg * 8;
        const size_t a1 = ((size_t)row1 * NSTEP + t) * INL + kg * 8;
        #pragma unroll 4
        for (int kb = 0; kb < INL; kb += 32) {
            s16x8 av0 = load8<FP32>(x, a0 + kb);
            s16x8 av1 = load8<FP32>(x, a1 + kb);
            s16x8 bv  = load8<FP32>(Wg, woff + kb);
            acc0 = __builtin_amdgcn_mfma_f32_16x16x32_bf16(av0, bv, acc0, 0, 0, 0);
            acc1 = __builtin_amdgcn_mfma_f32_16x16x32_bf16(av1, bv, acc1, 0, 0, 0);
        }
    }
    {
        const unsigned short* a0 = hprev + (size_t)row0 * HL + kg * 8;
        const unsigned short* a1 = hprev + (size_t)row1 * HL + kg * 8;
        const size_t w2 = woff + INL;
        #pragma unroll 4
        for (int kb = 0; kb < HL; kb += 32) {
            s16x8 av0 = *(const s16x8*)(a0 + kb);
            s16x8 av1 = *(const s16x8*)(a1 + kb);
            s16x8 bv  = load8<FP32>(Wg, w2 + kb);
            acc0 = __builtin_amdgcn_mfma_f32_16x16x32_bf16(av0, bv, acc0, 0, 0, 0);
            acc1 = __builtin_amdgcn_mfma_f32_16x16x32_bf16(av1, bv, acc1, 0, 0, 0);
        }
    }
    __shared__ float lg[4][4][B_];
    #pragma unroll
    for (int i = 0; i < 4; ++i) {
        lg[g][jj][wv * 32 + kg * 4 + i]      = acc0[i];
        lg[g][jj][wv * 32 + 16 + kg * 4 + i] = acc1[i];
    }
    __syncthreads();
    #pragma unroll
    for (int p = 0; p < 2; ++p) {
        const int idx = tid + p * 256;
        const int b   = idx & 127;
        const int jl  = idx >> 7;
        const int jg  = j0 + jl;
        const float z  = tanhf   (sane(lg[0][jl][b] + ld1<FP32>(bz,  t * CL + jg), 30.f));
        const float zi = sigmoidf_(sane(lg[1][jl][b] + ld1<FP32>(bi,  t * CL + jg), 30.f));
        const float zf = sigmoidf_(sane(lg[2][jl][b] + ld1<FP32>(bfg, t * CL + jg), 30.f));
        const float zo = sigmoidf_(sane(lg[3][jl][b] + ld1<FP32>(bo,  t * CL + jg), 30.f));
        const float cold = (float)c[(size_t)b * CL + jg];
        const float cn   = sane(zf * cold + zi * z, 50.f);
        c[(size_t)b * CL + jg] = (_Float16)cn;
        hnext[(size_t)b * HL + jg] = f2bf(zo * tanhf(cn));
    }
}

__global__ __launch_bounds__(256, 1) void gate_cell_kernel(
    const void* x, const void* W, const void* Wi, const void* Wf, const void* Wo,
    const void* bz, const void* bi, const void* bfg, const void* bo,
    const int* __restrict__ flag, _Float16* c,
    const unsigned short* hprev, unsigned short* hnext, int t)
{
    if (*flag) gate_body<1>(x, W, Wi, Wf, Wo, bz, bi, bfg, bo, c, hprev, hnext, t);
    else       gate_body<0>(x, W, Wi, Wf, Wo, bz, bi, bfg, bo, c, hprev, hnext, t);
}

template<int FP32>
__device__ __forceinline__ void outproj_body(
    const unsigned short* __restrict__ h, const void* __restrict__ Wout,
    const void* __restrict__ bout, float* __restrict__ out, int t)
{
    const int tid  = threadIdx.x;
    const int lane = tid & 63;
    const int wv   = tid >> 6;
    const int o    = blockIdx.x * 16 + (lane & 15);
    const int kg   = lane >> 4;
    const size_t woff = ((size_t)t * OUTL + o) * HL + kg * 8;
    const int row0 = wv * 32 + (lane & 15);
    const int row1 = row0 + 16;
    const unsigned short* a0 = h + (size_t)row0 * HL + kg * 8;
    const unsigned short* a1 = h + (size_t)row1 * HL + kg * 8;

    f32x4 acc0 = {0.f, 0.f, 0.f, 0.f};
    f32x4 acc1 = {0.f, 0.f, 0.f, 0.f};
    #pragma unroll 4
    for (int kb = 0; kb < HL; kb += 32) {
        s16x8 av0 = *(const s16x8*)(a0 + kb);
        s16x8 av1 = *(const s16x8*)(a1 + kb);
        s16x8 bv  = load8<FP32>(Wout, woff + kb);
        acc0 = __builtin_amdgcn_mfma_f32_16x16x32_bf16(av0, bv, acc0, 0, 0, 0);
        acc1 = __builtin_amdgcn_mfma_f32_16x16x32_bf16(av1, bv, acc1, 0, 0, 0);
    }
    const float bb = ld1<FP32>(bout, (size_t)t * OUTL + o);
    #pragma unroll
    for (int i = 0; i < 4; ++i) {
        const int r0 = wv * 32 + kg * 4 + i;
        out[(size_t)r0 * (NSTEP * OUTL) + (size_t)t * OUTL + o] =
            sigmoidf_(sane(acc0[i] + bb, 30.f));
        out[(size_t)(r0 + 16) * (NSTEP * OUTL) + (size_t)t * OUTL + o] =
            sigmoidf_(sane(acc1[i] + bb, 30.f));
    }
}

__global__ __launch_bounds__(256, 1) void outproj_kernel(
    const unsigned short* h, const void* Wout, const void* bout,
    const int* __restrict__ flag, float* out, int t)
{
    if (*flag) outproj_body<1>(h, Wout, bout, out, t);
    else       outproj_body<0>(h, Wout, bout, out, t);
}

__global__ void init_kernel(const void* c0, const void* h0, const int* __restrict__ flag,
                            _Float16* __restrict__ c,
                            unsigned short* __restrict__ hA,
                            unsigned short* __restrict__ hB)
{
    const int f   = *flag;
    const int idx = blockIdx.x * blockDim.x + threadIdx.x;
    if (idx < B_ * CL) {
        const int j = idx & (CL - 1);
        const float cv = f ? ((const float*)c0)[j] : bits2f(((const unsigned short*)c0)[j]);
        const float hv = f ? ((const float*)h0)[j] : bits2f(((const unsigned short*)h0)[j]);
        c[idx]  = (_Float16)cv;
        const unsigned short hb = f2bf(hv);
        hA[idx] = hb;
        hB[idx] = hb;
    }
}

// ===========================================================================
extern "C" void kernel_launch(void* const* d_in, const int* in_sizes, int n_in,
                              void* d_out, int out_size, void* d_ws, size_t ws_size,
                              hipStream_t stream)
{
    const void* x    = d_in[0];
    const void* W    = d_in[1];
    const void* Wi   = d_in[2];
    const void* Wf   = d_in[3];
    const void* Wo   = d_in[4];
    const void* Wout = d_in[5];
    const void* bz   = d_in[6];
    const void* bi   = d_in[7];
    const void* bfg  = d_in[8];
    const void* bo   = d_in[9];
    const void* bout = d_in[10];
    const void* c0   = d_in[11];
    const void* h0   = d_in[12];

    char* ws  = (char*)d_ws;
    int* flag = (int*)ws;
    float* out = (float*)d_out;   // OUTPUT IS FP32 (R4/R5 evidence)

    detect_kernel<<<1, 256, 0, stream>>>((const unsigned*)x, flag);

    if (ws_size >= (size_t)FWS_END) {
        // ---------------- full path ----------------
        float*          c  = (float*)(ws + FWS_C);
        unsigned short* hA = (unsigned short*)(ws + FWS_HA);
        unsigned short* hB = (unsigned short*)(ws + FWS_HB);
        _Float16*       XW = (_Float16*)(ws + FWS_XW);

        init_full_kernel<<<512, 256, 0, stream>>>(c0, h0, flag, c, hA, hB);
        xw_kernel<<<NSTEP * 256, 256, 0, stream>>>(x, W, Wi, Wf, Wo, flag, XW);

        for (int t = 0; t < NSTEP; ++t) {
            const unsigned short* hp = (t & 1) ? hB : hA;
            unsigned short*       hn = (t & 1) ? hA : hB;
            step_kernel<<<1088, 256, 0, stream>>>(
                W, Wi, Wf, Wo, bz, bi, bfg, bo, Wout, bout,
                flag, XW, c, hp, hn, out, t);
        }
        // h(24) lives in hA (t=23 odd wrote hA)
        outproj_final_kernel<<<64, 256, 0, stream>>>(hA, Wout, bout, flag, out);
    } else {
        // ---------------- fallback (R5 proven) ----------------
        _Float16*       c  = (_Float16*)(ws + WS_C);
        unsigned short* hA = (unsigned short*)(ws + WS_HA);
        unsigned short* hB = (unsigned short*)(ws + WS_HB);

        init_kernel<<<512, 256, 0, stream>>>(c0, h0, flag, c, hA, hB);
        for (int t = 0; t < NSTEP; ++t) {
            const unsigned short* hp = (t & 1) ? hB : hA;
            unsigned short*       hn = (t & 1) ? hA : hB;
            gate_cell_kernel<<<256, 256, 0, stream>>>(
                x, W, Wi, Wf, Wo, bz, bi, bfg, bo, flag, c, hp, hn, t);
            outproj_kernel<<<16, 256, 0, stream>>>(hn, Wout, bout, flag, out, t);
        }
    }
}